// Round 10
// baseline (424.792 us; speedup 1.0000x reference)
//
#include <hip/hip_runtime.h>
#include <math.h>

// ---------------------------------------------------------------------------
// GCN forward: gcn_norm (self-loops) -> [GEMM + CSR-aggregate + bias + relu] x2
//              -> segment_max pool (fused into agg2 via int atomicMax)
//              -> small FC.
// R5: GEMM1 = split-bf16 MFMA. R7: h1/h2 stored bf16 (best total 367us).
// R8 post-mortem: VMEM-inst-count model falsified; ~55 cyc/edge is a gather
//     latency floor. R9: revert aggs to R7 shape; fuse GEMM2 into agg1
//     epilogue (readlane-broadcast dot, fp32 W2 pairs from L1) -> removes
//     k_gemm2 kernel + the 25.6MB a1 buffer round-trip, zero precision cost.
// ---------------------------------------------------------------------------

typedef __attribute__((ext_vector_type(8))) short bfrag;   // 8 bf16 (4 VGPRs)
typedef __attribute__((ext_vector_type(4))) float ffrag;   // MFMA accumulator

__device__ inline void bf16split(float f, short& hi, short& lo) {
    unsigned u = __float_as_uint(f);
    unsigned r = u + 0x7fffu + ((u >> 16) & 1u);            // RNE to bf16
    unsigned short h = (unsigned short)(r >> 16);
    float hf = __uint_as_float(((unsigned)h) << 16);
    float lf = f - hf;
    unsigned ul = __float_as_uint(lf);
    unsigned rl = ul + 0x7fffu + ((ul >> 16) & 1u);
    hi = (short)h;
    lo = (short)(rl >> 16);
}

__device__ inline unsigned short f2bf(float f) {
    unsigned u = __float_as_uint(f);
    unsigned r = u + 0x7fffu + ((u >> 16) & 1u);            // RNE
    return (unsigned short)(r >> 16);
}

__device__ inline float bfl(unsigned u) { return __uint_as_float(u << 16); }
__device__ inline float bfh(unsigned u) { return __uint_as_float(u & 0xffff0000u); }

__global__ __launch_bounds__(256) void k_zero(int* __restrict__ cnt, int* __restrict__ pool,
                                              int n1, int n2) {
    int i = blockIdx.x * 256 + threadIdx.x;
    if (i < n1) cnt[i] = 0;
    if (i < n2) pool[i] = 0;
}

__global__ __launch_bounds__(256) void k_count(const int* __restrict__ ei, int* __restrict__ cnt,
                                               int E) {
    int e = blockIdx.x * 256 + threadIdx.x;
    if (e < E) atomicAdd(&cnt[ei[E + e]], 1);
}

__global__ __launch_bounds__(256) void k_dis(const int* __restrict__ cnt, float* __restrict__ dis,
                                             int N) {
    int v = blockIdx.x * 256 + threadIdx.x;
    if (v < N) dis[v] = 1.0f / sqrtf((float)(cnt[v] + 1));  // +1 self-loop
}

__global__ __launch_bounds__(1024) void k_scan_block(const int* __restrict__ cnt,
                                                     int* __restrict__ rowptr,
                                                     int* __restrict__ bsum, int N) {
    __shared__ int lds[1024];
    int t = threadIdx.x;
    int i = blockIdx.x * 1024 + t;
    int val = (i < N) ? cnt[i] : 0;
    lds[t] = val;
    __syncthreads();
    for (int off = 1; off < 1024; off <<= 1) {
        int u = (t >= off) ? lds[t - off] : 0;
        __syncthreads();
        lds[t] += u;
        __syncthreads();
    }
    if (i < N) rowptr[i] = lds[t] - val;  // exclusive within block
    if (t == 1023) bsum[blockIdx.x] = lds[1023];
}

__global__ __launch_bounds__(1024) void k_scan_tot(const int* __restrict__ bsum,
                                                   int* __restrict__ bsum2, int nb) {
    __shared__ int lds[1024];
    int t = threadIdx.x;
    int val = (t < nb) ? bsum[t] : 0;
    lds[t] = val;
    __syncthreads();
    for (int off = 1; off < 1024; off <<= 1) {
        int u = (t >= off) ? lds[t - off] : 0;
        __syncthreads();
        lds[t] += u;
        __syncthreads();
    }
    if (t < nb) bsum2[t] = lds[t] - val;  // exclusive
}

__global__ __launch_bounds__(256) void k_scan_add(int* __restrict__ rowptr, int* __restrict__ cursor,
                                                  const int* __restrict__ bsum2, int N, int E) {
    int i = blockIdx.x * 256 + threadIdx.x;
    if (i < N) {
        int r = rowptr[i] + bsum2[i >> 10];
        rowptr[i] = r;
        cursor[i] = r;
    }
    if (i == 0) rowptr[N] = E;
}

// packed CSR entry: .x = src index (int bits), .y = edge weight
__global__ __launch_bounds__(256) void k_fill(const int* __restrict__ ei,
                                              const float* __restrict__ dis,
                                              int* __restrict__ cursor,
                                              float2* __restrict__ csr, int E) {
    int e = blockIdx.x * 256 + threadIdx.x;
    if (e >= E) return;
    int r = ei[e];
    int c = ei[E + e];
    int p = atomicAdd(&cursor[c], 1);
    csr[p] = make_float2(__int_as_float(r), dis[r] * dis[c]);
}

// Pre-split W1 (256x128 fp32) into k-major bf16 hi/lo: Wt[col][k] (col=0..127).
__global__ __launch_bounds__(256) void k_wsplit(const float* __restrict__ W,
                                                short* __restrict__ wt_hi,
                                                short* __restrict__ wt_lo) {
    int i = blockIdx.x * 256 + threadIdx.x;
    if (i >= 256 * 128) return;
    int k = i >> 7, c = i & 127;
    short hi, lo;
    bf16split(W[i], hi, lo);
    wt_hi[c * 256 + k] = hi;
    wt_lo[c * 256 + k] = lo;
}

// Pair W2 (128x64 fp32) by k: w2p[kk*64+c] = (W2[2kk][c], W2[2kk+1][c]).
__global__ __launch_bounds__(256) void k_w2pair(const float* __restrict__ W2,
                                                float2* __restrict__ w2p) {
    int i = blockIdx.x * 256 + threadIdx.x;
    if (i >= 64 * 64) return;
    int kk = i >> 6, c = i & 63;
    w2p[i] = make_float2(W2[(2 * kk) * 64 + c], W2[(2 * kk + 1) * 64 + c]);
}

// ---------------------------------------------------------------------------
// GEMM1 via MFMA: h1b[M x 128] (bf16) = A[M x 256] @ W1, split-bf16.
// ---------------------------------------------------------------------------
__global__ __launch_bounds__(256) void k_gemm1_mfma(const float* __restrict__ A,
                                                    const short* __restrict__ wt_hi,
                                                    const short* __restrict__ wt_lo,
                                                    unsigned short* __restrict__ C, int M) {
    constexpr int KD = 256;
    __shared__ short Ah[64][40];
    __shared__ short Al[64][40];

    const int t = threadIdx.x;
    const int lane = t & 63;
    const int wid = t >> 6;      // 0..3
    const int wr = wid >> 1;     // wave row: rows wr*32..+31
    const int wc = wid & 1;      // wave col: cols wc*64..+63
    const int row0 = blockIdx.x * 64;
    const int lrow = lane & 15;
    const int lkg = lane >> 4;

    ffrag acc[2][4];
#pragma unroll
    for (int mr = 0; mr < 2; mr++)
#pragma unroll
        for (int nr = 0; nr < 4; nr++)
#pragma unroll
            for (int q = 0; q < 4; q++) acc[mr][nr][q] = 0.f;

    for (int kc = 0; kc < KD; kc += 32) {
#pragma unroll
        for (int i = 0; i < 2; i++) {
            int s = t * 2 + i;
            int m = s >> 3;           // row in tile
            int kq = s & 7;           // float4 index in k-chunk
            int r = row0 + m;
            float4 v = make_float4(0.f, 0.f, 0.f, 0.f);
            if (r < M) v = *(const float4*)&A[(size_t)r * KD + kc + kq * 4];
            short4 sh, sl;
            bf16split(v.x, sh.x, sl.x);
            bf16split(v.y, sh.y, sl.y);
            bf16split(v.z, sh.z, sl.z);
            bf16split(v.w, sh.w, sl.w);
            *(short4*)&Ah[m][kq * 4] = sh;
            *(short4*)&Al[m][kq * 4] = sl;
        }
        __syncthreads();

        bfrag ahi[2], alo[2];
#pragma unroll
        for (int mr = 0; mr < 2; mr++) {
            int arow = wr * 32 + mr * 16 + lrow;
            ahi[mr] = *(const bfrag*)&Ah[arow][lkg * 8];
            alo[mr] = *(const bfrag*)&Al[arow][lkg * 8];
        }
#pragma unroll
        for (int nr = 0; nr < 4; nr++) {
            int col = wc * 64 + nr * 16 + lrow;
            const size_t boff = (size_t)col * 256 + kc + lkg * 8;
            bfrag bhi = *(const bfrag*)&wt_hi[boff];
            bfrag blo = *(const bfrag*)&wt_lo[boff];
#pragma unroll
            for (int mr = 0; mr < 2; mr++) {
                acc[mr][nr] = __builtin_amdgcn_mfma_f32_16x16x32_bf16(ahi[mr], bhi, acc[mr][nr], 0, 0, 0);
                acc[mr][nr] = __builtin_amdgcn_mfma_f32_16x16x32_bf16(ahi[mr], blo, acc[mr][nr], 0, 0, 0);
                acc[mr][nr] = __builtin_amdgcn_mfma_f32_16x16x32_bf16(alo[mr], bhi, acc[mr][nr], 0, 0, 0);
            }
        }
        __syncthreads();
    }

#pragma unroll
    for (int mr = 0; mr < 2; mr++)
#pragma unroll
        for (int nr = 0; nr < 4; nr++)
#pragma unroll
            for (int q = 0; q < 4; q++) {
                int rr = row0 + wr * 32 + mr * 16 + lkg * 4 + q;
                int cc = wc * 64 + nr * 16 + lrow;
                if (rr < M) C[(size_t)rr * 128 + cc] = f2bf(acc[mr][nr][q]);
            }
}

// ---------------------------------------------------------------------------
// Fused layer-1 aggregate + GEMM2: one wave/node.
// Gather phase = exact R7 agg1 (uint gathers of bf16 h1, flat U=8).
// Epilogue: a1 row lives in registers (2 feats/lane, fp32); compute
// h2_pre[v][lane] = sum_k a1[k]*W2[k][lane] via readlane broadcasts +
// coalesced fp32 W2-pair loads (32KB, L1/L2-hot). No LDS, no a1 buffer.
// ---------------------------------------------------------------------------
__global__ __launch_bounds__(256) void k_agg1_g2(const unsigned int* __restrict__ h1b, // [N][64]
                                                 const int* __restrict__ rowptr,
                                                 const float2* __restrict__ csr,
                                                 const float* __restrict__ dis,
                                                 const float* __restrict__ b1,
                                                 const float2* __restrict__ w2p, // [64][64]
                                                 unsigned short* __restrict__ h2b, int N) {
    int wave = (blockIdx.x * 256 + threadIdx.x) >> 6;
    int lane = threadIdx.x & 63;
    if (wave >= N) return;
    const int v = wave;
    float d = dis[v];
    float ds2 = d * d;
    unsigned hv = h1b[(size_t)v * 64 + lane];
    float ax = ds2 * bfl(hv);           // feat 2*lane
    float ay = ds2 * bfh(hv);           // feat 2*lane+1
    int s0 = rowptr[v], s1 = rowptr[v + 1];
    for (int j = s0; j < s1; j += 8) {
        int   uu[8];
        float ww[8];
#pragma unroll
        for (int q = 0; q < 8; q++) {
            int jj = j + q;
            bool ok = jj < s1;
            float2 e = csr[ok ? jj : s0];
            uu[q] = ok ? __float_as_int(e.x) : 0;
            ww[q] = ok ? e.y : 0.f;
        }
        unsigned g[8];
#pragma unroll
        for (int q = 0; q < 8; q++) g[q] = h1b[(size_t)uu[q] * 64 + lane];
#pragma unroll
        for (int q = 0; q < 8; q++) {
            ax += ww[q] * bfl(g[q]);
            ay += ww[q] * bfh(g[q]);
        }
    }
    float2 bb = *(const float2*)&b1[lane * 2];
    float a0 = fmaxf(ax + bb.x, 0.f);   // a1[v][2*lane]
    float a1v = fmaxf(ay + bb.y, 0.f);  // a1[v][2*lane+1]

    // GEMM2 epilogue: h2_pre[v][lane] (no bias here; b2 applied after agg2)
    float acc = 0.f;
#pragma unroll 8
    for (int kk = 0; kk < 64; kk++) {
        float2 w = w2p[kk * 64 + lane];   // (W2[2kk][lane], W2[2kk+1][lane])
        float e0 = __shfl(a0, kk);        // a1[v][2kk]
        float e1 = __shfl(a1v, kk);       // a1[v][2kk+1]
        acc += e0 * w.x + e1 * w.y;
    }
    h2b[(size_t)v * 64 + lane] = f2bf(acc);
}

// Layer-2 aggregate: one wave/node, 64 bf16 feats (1 ushort/lane);
// fused bias+relu+graph max-pool. Flat U=8 batch (R7 shape).
__global__ __launch_bounds__(256) void k_agg2_pool(const unsigned short* __restrict__ h2b,
                                                   const int* __restrict__ rowptr,
                                                   const float2* __restrict__ csr,
                                                   const float* __restrict__ dis,
                                                   const float* __restrict__ b,
                                                   const int* __restrict__ batch,
                                                   float* __restrict__ pool, int N) {
    int wave = (blockIdx.x * 256 + threadIdx.x) >> 6;
    int lane = threadIdx.x & 63;
    if (wave >= N) return;
    const int v = wave;
    float d = dis[v];
    float ds2 = d * d;
    float acc = ds2 * __uint_as_float(((unsigned)h2b[(size_t)v * 64 + lane]) << 16);
    int s0 = rowptr[v], s1 = rowptr[v + 1];
    for (int j = s0; j < s1; j += 8) {
        int   uu[8];
        float ww[8];
#pragma unroll
        for (int q = 0; q < 8; q++) {
            int jj = j + q;
            bool ok = jj < s1;
            float2 e = csr[ok ? jj : s0];
            uu[q] = ok ? __float_as_int(e.x) : 0;
            ww[q] = ok ? e.y : 0.f;
        }
        unsigned short g[8];
#pragma unroll
        for (int q = 0; q < 8; q++) g[q] = h2b[(size_t)uu[q] * 64 + lane];
#pragma unroll
        for (int q = 0; q < 8; q++) acc += ww[q] * __uint_as_float(((unsigned)g[q]) << 16);
    }
    float val = fmaxf(acc + b[lane], 0.f);
    int g = batch[v];
    // val >= 0 so float bits order as signed ints; pool zero-initialized.
    atomicMax((int*)&pool[(size_t)g * 64 + lane], __float_as_int(val));
}

__global__ __launch_bounds__(256) void k_fc(const float* __restrict__ pool,
                                            const float* __restrict__ Wfc,
                                            const float* __restrict__ bfc,
                                            float* __restrict__ out, int G) {
    int t = blockIdx.x * 256 + threadIdx.x;
    if (t >= G * 10) return;
    int g = t / 10, o = t % 10;
    float acc = bfc[o];
#pragma unroll
    for (int f = 0; f < 64; f++) acc += pool[g * 64 + f] * Wfc[f * 10 + o];
    out[t] = acc;
}

extern "C" void kernel_launch(void* const* d_in, const int* in_sizes, int n_in,
                              void* d_out, int out_size, void* d_ws, size_t ws_size,
                              hipStream_t stream) {
    const float* x   = (const float*)d_in[0];
    const int*   ei  = (const int*)d_in[1];
    const int*   bat = (const int*)d_in[2];
    const float* W1  = (const float*)d_in[3];
    const float* b1  = (const float*)d_in[4];
    const float* W2  = (const float*)d_in[5];
    const float* b2  = (const float*)d_in[6];
    const float* Wfc = (const float*)d_in[7];
    const float* bfc = (const float*)d_in[8];
    float* out = (float*)d_out;

    const int N = in_sizes[2];          // 50000
    const int E = in_sizes[1] / 2;      // 800000
    const int G = out_size / 10;        // 128

    // workspace layout (256B aligned)
    char* ws = (char*)d_ws;
    size_t off = 0;
    auto alloc = [&](size_t bytes) -> char* {
        char* p = ws + off;
        off = (off + bytes + 255) & ~(size_t)255;
        return p;
    };
    int*    cnt    = (int*)alloc((size_t)N * 4);
    float*  dis    = (float*)alloc((size_t)N * 4);
    int*    rowptr = (int*)alloc((size_t)(N + 1) * 4);
    int*    cursor = (int*)alloc((size_t)N * 4);
    int*    bsum   = (int*)alloc(1024 * 4);
    int*    bsum2  = (int*)alloc(1024 * 4);
    float2* csr    = (float2*)alloc((size_t)E * 8);
    unsigned short* h1b = (unsigned short*)alloc((size_t)N * 128 * 2);
    unsigned short* h2b = (unsigned short*)alloc((size_t)N * 64 * 2);
    float*  pool   = (float*)alloc((size_t)G * 64 * 4);
    short*  wt_hi  = (short*)alloc(128 * 256 * 2);
    short*  wt_lo  = (short*)alloc(128 * 256 * 2);
    float2* w2p    = (float2*)alloc(64 * 64 * 8);
    (void)ws_size; (void)n_in;

    const int nb = (N + 1023) / 1024;

    // ---- gcn_norm + CSR build (+ weight prep) ----
    {
        int zmax = N > G * 64 ? N : G * 64;
        k_zero<<<(zmax + 255) / 256, 256, 0, stream>>>(cnt, (int*)pool, N, G * 64);
    }
    k_wsplit<<<128, 256, 0, stream>>>(W1, wt_hi, wt_lo);
    k_w2pair<<<16, 256, 0, stream>>>(W2, w2p);
    k_count<<<(E + 255) / 256, 256, 0, stream>>>(ei, cnt, E);
    k_dis<<<(N + 255) / 256, 256, 0, stream>>>(cnt, dis, N);
    k_scan_block<<<nb, 1024, 0, stream>>>(cnt, rowptr, bsum, N);
    k_scan_tot<<<1, 1024, 0, stream>>>(bsum, bsum2, nb);
    k_scan_add<<<(N + 255) / 256, 256, 0, stream>>>(rowptr, cursor, bsum2, N, E);
    k_fill<<<(E + 255) / 256, 256, 0, stream>>>(ei, dis, cursor, csr, E);

    // ---- layer 1 GEMM (MFMA split-bf16 -> bf16 h1) ----
    k_gemm1_mfma<<<(N + 63) / 64, 256, 0, stream>>>(x, wt_hi, wt_lo, h1b, N);

    // ---- fused: layer-1 aggregate + GEMM2 -> bf16 h2 ----
    k_agg1_g2<<<(N * 64 + 255) / 256, 256, 0, stream>>>((const unsigned int*)h1b, rowptr, csr,
                                                        dis, b1, w2p, h2b, N);

    // ---- layer-2 aggregate + bias + relu + graph max-pool ----
    k_agg2_pool<<<(N * 64 + 255) / 256, 256, 0, stream>>>(h2b, rowptr, csr, dis, b2, bat,
                                                          pool, N);

    // ---- FC head ----
    k_fc<<<(G * 10 + 255) / 256, 256, 0, stream>>>(pool, Wfc, bfc, out, G);
}

// Round 14
// 357.920 us; speedup vs baseline: 1.1868x; 1.1868x over previous
//
#include <hip/hip_runtime.h>
#include <math.h>

// ---------------------------------------------------------------------------
// GCN forward: gcn_norm (self-loops) -> [GEMM + CSR-aggregate + bias + relu] x2
//              -> segment_max pool (fused into agg2 via int atomicMax)
//              -> small FC.
// R7 structure (best 367us). R10:
//  - dis-prescaling: h stored as hs = bf16(dis*h) in GEMM epilogues;
//    agg[c] = dis[c]*(sum hs[r] + hs[c]) -> CSR = 4B index only, no weight.
//  - kernel count 13 -> 10 (prep fused; dis folded into scan; scan_tot+add merged).
//  - agg loop shape EXACTLY R7 (flat U=8, one gather/edge) - empirical floor.
// (Resubmitted unchanged after 3x GPU acquisition timeout.)
// ---------------------------------------------------------------------------

typedef __attribute__((ext_vector_type(8))) short bfrag;   // 8 bf16 (4 VGPRs)
typedef __attribute__((ext_vector_type(4))) float ffrag;   // MFMA accumulator

__device__ inline void bf16split(float f, short& hi, short& lo) {
    unsigned u = __float_as_uint(f);
    unsigned r = u + 0x7fffu + ((u >> 16) & 1u);            // RNE to bf16
    unsigned short h = (unsigned short)(r >> 16);
    float hf = __uint_as_float(((unsigned)h) << 16);
    float lf = f - hf;
    unsigned ul = __float_as_uint(lf);
    unsigned rl = ul + 0x7fffu + ((ul >> 16) & 1u);
    hi = (short)h;
    lo = (short)(rl >> 16);
}

__device__ inline unsigned short f2bf(float f) {
    unsigned u = __float_as_uint(f);
    unsigned r = u + 0x7fffu + ((u >> 16) & 1u);            // RNE
    return (unsigned short)(r >> 16);
}

__device__ inline float bfl(unsigned u) { return __uint_as_float(u << 16); }
__device__ inline float bfh(unsigned u) { return __uint_as_float(u & 0xffff0000u); }

// prep: zero cnt + pool, split W1 into k-major bf16 hi/lo. One kernel.
__global__ __launch_bounds__(256) void k_prep(int* __restrict__ cnt, int* __restrict__ pool,
                                              const float* __restrict__ W1,
                                              short* __restrict__ wt_hi,
                                              short* __restrict__ wt_lo,
                                              int n1, int n2) {
    int i = blockIdx.x * 256 + threadIdx.x;
    if (i < n1) cnt[i] = 0;
    if (i < n2) pool[i] = 0;
    if (i < 256 * 128) {
        int k = i >> 7, c = i & 127;
        short hi, lo;
        bf16split(W1[i], hi, lo);
        wt_hi[c * 256 + k] = hi;
        wt_lo[c * 256 + k] = lo;
    }
}

__global__ __launch_bounds__(256) void k_count(const int* __restrict__ ei, int* __restrict__ cnt,
                                               int E) {
    int e = blockIdx.x * 256 + threadIdx.x;
    if (e < E) atomicAdd(&cnt[ei[E + e]], 1);
}

// block-local exclusive scan (1024/block) + dis = rsqrt(deg+1)
__global__ __launch_bounds__(1024) void k_scan_dis(const int* __restrict__ cnt,
                                                   int* __restrict__ rowptr,
                                                   int* __restrict__ bsum,
                                                   float* __restrict__ dis, int N) {
    __shared__ int lds[1024];
    int t = threadIdx.x;
    int i = blockIdx.x * 1024 + t;
    int val = (i < N) ? cnt[i] : 0;
    if (i < N) dis[i] = 1.0f / sqrtf((float)(val + 1));  // +1 self-loop
    lds[t] = val;
    __syncthreads();
    for (int off = 1; off < 1024; off <<= 1) {
        int u = (t >= off) ? lds[t - off] : 0;
        __syncthreads();
        lds[t] += u;
        __syncthreads();
    }
    if (i < N) rowptr[i] = lds[t] - val;  // exclusive within block
    if (t == 1023) bsum[blockIdx.x] = lds[1023];
}

// finish scan: every block redundantly prefix-sums bsum (nb <= 128), adds.
__global__ __launch_bounds__(256) void k_scan_fin(int* __restrict__ rowptr,
                                                  int* __restrict__ cursor,
                                                  const int* __restrict__ bsum,
                                                  int nb, int N, int E) {
    __shared__ int pre[128];
    int t = threadIdx.x;
    if (t == 0) {
        int run = 0;
        for (int q = 0; q < nb; q++) { pre[q] = run; run += bsum[q]; }
    }
    __syncthreads();
    int i = blockIdx.x * 256 + t;
    if (i < N) {
        int r = rowptr[i] + pre[i >> 10];
        rowptr[i] = r;
        cursor[i] = r;
    }
    if (i == 0) rowptr[N] = E;
}

// CSR fill: index only (4B/edge); weights are folded into prescaled h.
__global__ __launch_bounds__(256) void k_fill(const int* __restrict__ ei,
                                              int* __restrict__ cursor,
                                              int* __restrict__ csr_i, int E) {
    int e = blockIdx.x * 256 + threadIdx.x;
    if (e >= E) return;
    int r = ei[e];
    int c = ei[E + e];
    int p = atomicAdd(&cursor[c], 1);
    csr_i[p] = r;
}

// ---------------------------------------------------------------------------
// GEMM1 via MFMA: hs1[M x 128] = bf16(dis[m] * (A[M x 256] @ W1)), split-bf16.
// ---------------------------------------------------------------------------
__global__ __launch_bounds__(256) void k_gemm1_mfma(const float* __restrict__ A,
                                                    const short* __restrict__ wt_hi,
                                                    const short* __restrict__ wt_lo,
                                                    const float* __restrict__ dis,
                                                    unsigned short* __restrict__ C, int M) {
    constexpr int KD = 256;
    __shared__ short Ah[64][40];
    __shared__ short Al[64][40];

    const int t = threadIdx.x;
    const int lane = t & 63;
    const int wid = t >> 6;      // 0..3
    const int wr = wid >> 1;     // wave row: rows wr*32..+31
    const int wc = wid & 1;      // wave col: cols wc*64..+63
    const int row0 = blockIdx.x * 64;
    const int lrow = lane & 15;
    const int lkg = lane >> 4;

    ffrag acc[2][4];
#pragma unroll
    for (int mr = 0; mr < 2; mr++)
#pragma unroll
        for (int nr = 0; nr < 4; nr++)
#pragma unroll
            for (int q = 0; q < 4; q++) acc[mr][nr][q] = 0.f;

    for (int kc = 0; kc < KD; kc += 32) {
#pragma unroll
        for (int i = 0; i < 2; i++) {
            int s = t * 2 + i;
            int m = s >> 3;           // row in tile
            int kq = s & 7;           // float4 index in k-chunk
            int r = row0 + m;
            float4 v = make_float4(0.f, 0.f, 0.f, 0.f);
            if (r < M) v = *(const float4*)&A[(size_t)r * KD + kc + kq * 4];
            short4 sh, sl;
            bf16split(v.x, sh.x, sl.x);
            bf16split(v.y, sh.y, sl.y);
            bf16split(v.z, sh.z, sl.z);
            bf16split(v.w, sh.w, sl.w);
            *(short4*)&Ah[m][kq * 4] = sh;
            *(short4*)&Al[m][kq * 4] = sl;
        }
        __syncthreads();

        bfrag ahi[2], alo[2];
#pragma unroll
        for (int mr = 0; mr < 2; mr++) {
            int arow = wr * 32 + mr * 16 + lrow;
            ahi[mr] = *(const bfrag*)&Ah[arow][lkg * 8];
            alo[mr] = *(const bfrag*)&Al[arow][lkg * 8];
        }
#pragma unroll
        for (int nr = 0; nr < 4; nr++) {
            int col = wc * 64 + nr * 16 + lrow;
            const size_t boff = (size_t)col * 256 + kc + lkg * 8;
            bfrag bhi = *(const bfrag*)&wt_hi[boff];
            bfrag blo = *(const bfrag*)&wt_lo[boff];
#pragma unroll
            for (int mr = 0; mr < 2; mr++) {
                acc[mr][nr] = __builtin_amdgcn_mfma_f32_16x16x32_bf16(ahi[mr], bhi, acc[mr][nr], 0, 0, 0);
                acc[mr][nr] = __builtin_amdgcn_mfma_f32_16x16x32_bf16(ahi[mr], blo, acc[mr][nr], 0, 0, 0);
                acc[mr][nr] = __builtin_amdgcn_mfma_f32_16x16x32_bf16(alo[mr], bhi, acc[mr][nr], 0, 0, 0);
            }
        }
        __syncthreads();
    }

#pragma unroll
    for (int mr = 0; mr < 2; mr++)
#pragma unroll
        for (int nr = 0; nr < 4; nr++)
#pragma unroll
            for (int q = 0; q < 4; q++) {
                int rr = row0 + wr * 32 + mr * 16 + lkg * 4 + q;
                int cc = wc * 64 + nr * 16 + lrow;
                if (rr < M) C[(size_t)rr * 128 + cc] = f2bf(dis[rr] * acc[mr][nr][q]);
            }
}

// ---------------------------------------------------------------------------
// fp32 VALU GEMM (layer 2): hs2[M x 64] = bf16(dis[m] * (a1[M x 128] @ W2))
// ---------------------------------------------------------------------------
__global__ __launch_bounds__(256) void k_gemm2(const float* __restrict__ A,
                                               const float* __restrict__ W,
                                               const float* __restrict__ dis,
                                               unsigned short* __restrict__ C, int M) {
    constexpr int KDIM = 128, NOUT = 64, BM = 64, BK = 32;
    __shared__ float As[BK][BM + 4];
    __shared__ float Ws[BK][NOUT];

    const int t = threadIdx.x;
    const int tx = t & 15;
    const int ty = t >> 4;
    const int row0 = blockIdx.x * BM;

    float acc[4][4];
#pragma unroll
    for (int r = 0; r < 4; r++)
#pragma unroll
        for (int c = 0; c < 4; c++) acc[r][c] = 0.f;

    for (int kc = 0; kc < KDIM; kc += BK) {
#pragma unroll
        for (int i = 0; i < 2; i++) {
            int s = t * 2 + i;
            int m = s >> 3;
            int kq = s & 7;
            int r = row0 + m;
            float4 v = make_float4(0.f, 0.f, 0.f, 0.f);
            if (r < M) v = *(const float4*)&A[(size_t)r * KDIM + kc + kq * 4];
            As[kq * 4 + 0][m] = v.x;
            As[kq * 4 + 1][m] = v.y;
            As[kq * 4 + 2][m] = v.z;
            As[kq * 4 + 3][m] = v.w;
        }
#pragma unroll
        for (int i = 0; i < 2; i++) {
            int s = t + i * 256;
            int k = s / 16;
            int c4 = s % 16;
            *(float4*)&Ws[k][c4 * 4] = *(const float4*)&W[(size_t)(kc + k) * NOUT + c4 * 4];
        }
        __syncthreads();

#pragma unroll
        for (int k = 0; k < BK; k++) {
            float4 a = *(const float4*)&As[k][ty * 4];
            float4 w0 = *(const float4*)&Ws[k][tx * 4];
            const float* ap = (const float*)&a;
            const float* w0p = (const float*)&w0;
#pragma unroll
            for (int r = 0; r < 4; r++)
#pragma unroll
                for (int c = 0; c < 4; c++) acc[r][c] += ap[r] * w0p[c];
        }
        __syncthreads();
    }

#pragma unroll
    for (int r = 0; r < 4; r++) {
        int rr = row0 + ty * 4 + r;
        if (rr < M) {
            float dd = dis[rr];
            ushort4 o;
            o.x = f2bf(dd * acc[r][0]);
            o.y = f2bf(dd * acc[r][1]);
            o.z = f2bf(dd * acc[r][2]);
            o.w = f2bf(dd * acc[r][3]);
            *(ushort4*)&C[(size_t)rr * NOUT + tx * 4] = o;
        }
    }
}

// Layer-1 aggregate: one wave/node, 128 bf16 feats as uint (2 feats)/lane.
// hs gathers are unweighted; out = relu(dis[v]*(sum + self) + b1), fp32.
__global__ __launch_bounds__(256) void k_agg1(const unsigned int* __restrict__ hs1, // [N][64]
                                              const int* __restrict__ rowptr,
                                              const int* __restrict__ csr_i,
                                              const float* __restrict__ dis,
                                              const float* __restrict__ b,
                                              float* __restrict__ out, int N) {
    int wave = (blockIdx.x * 256 + threadIdx.x) >> 6;
    int lane = threadIdx.x & 63;
    if (wave >= N) return;
    const int v = wave;
    unsigned hv = hs1[(size_t)v * 64 + lane];
    float ax = bfl(hv);           // feat 2*lane
    float ay = bfh(hv);           // feat 2*lane+1
    int s0 = rowptr[v], s1 = rowptr[v + 1];
    for (int j = s0; j < s1; j += 8) {
        int uu[8];
#pragma unroll
        for (int q = 0; q < 8; q++) {
            int jj = j + q;
            uu[q] = (jj < s1) ? csr_i[jj] : -1;
        }
        unsigned g[8];
#pragma unroll
        for (int q = 0; q < 8; q++) g[q] = (uu[q] >= 0) ? hs1[(size_t)uu[q] * 64 + lane] : 0u;
#pragma unroll
        for (int q = 0; q < 8; q++) {
            ax += bfl(g[q]);
            ay += bfh(g[q]);
        }
    }
    float d = dis[v];
    float2 bb = *(const float2*)&b[lane * 2];
    float2 o;
    o.x = fmaxf(d * ax + bb.x, 0.f);
    o.y = fmaxf(d * ay + bb.y, 0.f);
    *(float2*)&out[(size_t)v * 128 + lane * 2] = o;
}

// Layer-2 aggregate: one wave/node, 64 bf16 feats (1 ushort/lane);
// fused bias+relu+graph max-pool.
__global__ __launch_bounds__(256) void k_agg2_pool(const unsigned short* __restrict__ hs2,
                                                   const int* __restrict__ rowptr,
                                                   const int* __restrict__ csr_i,
                                                   const float* __restrict__ dis,
                                                   const float* __restrict__ b,
                                                   const int* __restrict__ batch,
                                                   float* __restrict__ pool, int N) {
    int wave = (blockIdx.x * 256 + threadIdx.x) >> 6;
    int lane = threadIdx.x & 63;
    if (wave >= N) return;
    const int v = wave;
    float acc = __uint_as_float(((unsigned)hs2[(size_t)v * 64 + lane]) << 16);
    int s0 = rowptr[v], s1 = rowptr[v + 1];
    for (int j = s0; j < s1; j += 8) {
        int uu[8];
#pragma unroll
        for (int q = 0; q < 8; q++) {
            int jj = j + q;
            uu[q] = (jj < s1) ? csr_i[jj] : -1;
        }
        unsigned short g[8];
#pragma unroll
        for (int q = 0; q < 8; q++)
            g[q] = (uu[q] >= 0) ? hs2[(size_t)uu[q] * 64 + lane] : (unsigned short)0;
#pragma unroll
        for (int q = 0; q < 8; q++) acc += __uint_as_float(((unsigned)g[q]) << 16);
    }
    float val = fmaxf(dis[v] * acc + b[lane], 0.f);
    int g = batch[v];
    // val >= 0 so float bits order as signed ints; pool zero-initialized.
    atomicMax((int*)&pool[(size_t)g * 64 + lane], __float_as_int(val));
}

__global__ __launch_bounds__(256) void k_fc(const float* __restrict__ pool,
                                            const float* __restrict__ Wfc,
                                            const float* __restrict__ bfc,
                                            float* __restrict__ out, int G) {
    int t = blockIdx.x * 256 + threadIdx.x;
    if (t >= G * 10) return;
    int g = t / 10, o = t % 10;
    float acc = bfc[o];
#pragma unroll
    for (int f = 0; f < 64; f++) acc += pool[g * 64 + f] * Wfc[f * 10 + o];
    out[t] = acc;
}

extern "C" void kernel_launch(void* const* d_in, const int* in_sizes, int n_in,
                              void* d_out, int out_size, void* d_ws, size_t ws_size,
                              hipStream_t stream) {
    const float* x   = (const float*)d_in[0];
    const int*   ei  = (const int*)d_in[1];
    const int*   bat = (const int*)d_in[2];
    const float* W1  = (const float*)d_in[3];
    const float* b1  = (const float*)d_in[4];
    const float* W2  = (const float*)d_in[5];
    const float* b2  = (const float*)d_in[6];
    const float* Wfc = (const float*)d_in[7];
    const float* bfc = (const float*)d_in[8];
    float* out = (float*)d_out;

    const int N = in_sizes[2];          // 50000
    const int E = in_sizes[1] / 2;      // 800000
    const int G = out_size / 10;        // 128

    // workspace layout (256B aligned)
    char* ws = (char*)d_ws;
    size_t off = 0;
    auto alloc = [&](size_t bytes) -> char* {
        char* p = ws + off;
        off = (off + bytes + 255) & ~(size_t)255;
        return p;
    };
    int*    cnt    = (int*)alloc((size_t)N * 4);
    float*  dis    = (float*)alloc((size_t)N * 4);
    int*    rowptr = (int*)alloc((size_t)(N + 1) * 4);
    int*    cursor = (int*)alloc((size_t)N * 4);
    int*    bsum   = (int*)alloc(1024 * 4);
    int*    csr_i  = (int*)alloc((size_t)E * 4);
    unsigned short* hs1 = (unsigned short*)alloc((size_t)N * 128 * 2);
    float*  a1     = (float*)alloc((size_t)N * 128 * 4);
    unsigned short* hs2 = (unsigned short*)alloc((size_t)N * 64 * 2);
    float*  pool   = (float*)alloc((size_t)G * 64 * 4);
    short*  wt_hi  = (short*)alloc(128 * 256 * 2);
    short*  wt_lo  = (short*)alloc(128 * 256 * 2);
    (void)ws_size; (void)n_in;

    const int nb = (N + 1023) / 1024;
    const int nb256 = (N + 255) / 256;

    // ---- prep + gcn_norm + CSR build (5 kernels) ----
    k_prep<<<nb256, 256, 0, stream>>>(cnt, (int*)pool, W1, wt_hi, wt_lo, N, G * 64);
    k_count<<<(E + 255) / 256, 256, 0, stream>>>(ei, cnt, E);
    k_scan_dis<<<nb, 1024, 0, stream>>>(cnt, rowptr, bsum, dis, N);
    k_scan_fin<<<nb256, 256, 0, stream>>>(rowptr, cursor, bsum, nb, N, E);
    k_fill<<<(E + 255) / 256, 256, 0, stream>>>(ei, cursor, csr_i, E);

    // ---- layer 1: MFMA GEMM (dis-prescaled bf16 out) + aggregate ----
    k_gemm1_mfma<<<(N + 63) / 64, 256, 0, stream>>>(x, wt_hi, wt_lo, dis, hs1, N);
    k_agg1<<<(N * 64 + 255) / 256, 256, 0, stream>>>((const unsigned int*)hs1, rowptr, csr_i,
                                                     dis, b1, a1, N);

    // ---- layer 2: fp32 GEMM (dis-prescaled bf16 out) + aggregate + pool ----
    k_gemm2<<<(N + 63) / 64, 256, 0, stream>>>(a1, W2, dis, hs2, N);
    k_agg2_pool<<<(N * 64 + 255) / 256, 256, 0, stream>>>(hs2, rowptr, csr_i, dis, b2, bat,
                                                          pool, N);

    // ---- FC head ----
    k_fc<<<(G * 10 + 255) / 256, 256, 0, stream>>>(pool, Wfc, bfc, out, G);
}